// Round 2
// baseline (1286.665 us; speedup 1.0000x reference)
//
#include <hip/hip_runtime.h>
#include <stdint.h>

typedef unsigned short u16;
typedef short s16x8 __attribute__((ext_vector_type(8)));
typedef float f32x4 __attribute__((ext_vector_type(4)));

__device__ __forceinline__ float bf2f(u16 u) {
  union { unsigned u; float f; } c; c.u = ((unsigned)u) << 16; return c.f;
}
__device__ __forceinline__ u16 f2bf(float f) {
  union { float f; unsigned u; } c; c.f = f;
  unsigned r = c.u + 0x7FFFu + ((c.u >> 16) & 1u);
  return (u16)(r >> 16);
}
__device__ __forceinline__ unsigned encf(float x) {
  union { float f; unsigned u; } c; c.f = x;
  return (c.u & 0x80000000u) ? ~c.u : (c.u | 0x80000000u);
}
__device__ __forceinline__ float decf(unsigned e) {
  union { unsigned u; float f; } c;
  c.u = (e & 0x80000000u) ? (e ^ 0x80000000u) : ~e;
  return c.f;
}
__device__ __forceinline__ f32x4 mfma16(s16x8 a, s16x8 b, f32x4 c) {
  return __builtin_amdgcn_mfma_f32_16x16x32_bf16(a, b, c, 0, 0, 0);
}
__device__ __forceinline__ float relu(float x) { return x > 0.f ? x : 0.f; }

// ---- dtype-generic loaders: element index ei, F32 selects f32 vs bf16 buffers ----
template <int F32>
__device__ __forceinline__ void loadf8(const void* p, size_t ei, float* o) {
  if (F32) {
    const float* f = (const float*)p + ei;
    f32x4 a = *(const f32x4*)f;
    f32x4 b = *(const f32x4*)(f + 4);
#pragma unroll
    for (int j = 0; j < 4; ++j) { o[j] = a[j]; o[4 + j] = b[j]; }
  } else {
    s16x8 v = *(const s16x8*)((const u16*)p + ei);
#pragma unroll
    for (int j = 0; j < 8; ++j) o[j] = bf2f((u16)v[j]);
  }
}
template <int F32>
__device__ __forceinline__ s16x8 load8b(const void* p, size_t ei) {  // -> 8 bf16
  if (F32) {
    float o[8]; loadf8<1>(p, ei, o);
    s16x8 r;
#pragma unroll
    for (int j = 0; j < 8; ++j) r[j] = (short)f2bf(o[j]);
    return r;
  } else {
    return *(const s16x8*)((const u16*)p + ei);
  }
}
template <int F32>
__device__ __forceinline__ float ld1(const void* p, size_t ei) {
  return F32 ? ((const float*)p)[ei] : bf2f(((const u16*)p)[ei]);
}

// ---------------- detect dtype + init ws ----------------
// ws (u32): [0:64) egws, [64:192) rgws, [192:256) tpart, [256] flag (1 = f32)
__global__ void k_detect(const u16* __restrict__ entity, const u16* __restrict__ rel,
                         unsigned* __restrict__ ws) {
  __shared__ unsigned cnt[256];
  const int t = threadIdx.x;
  ws[t] = 0u;
  unsigned c = 0;
  for (int i = t; i < 16384; i += 256) {
    unsigned u = rel[i];
    if ((u & 0x7F80u) == 0x7F80u) ++c;  // exp all-ones: impossible in genuine bf16 data
  }
  for (int i = t; i < 8192; i += 256) {
    unsigned u = entity[i];
    if ((u & 0x7F80u) == 0x7F80u) ++c;
  }
  cnt[t] = c;
  __syncthreads();
  for (int st = 128; st > 0; st >>= 1) {
    if (t < st) cnt[t] += cnt[t + st];
    __syncthreads();
  }
  if (t == 0) ws[256] = cnt[0] ? 1u : 0u;
}

// ---------------- entity encoder: 2048 rows, 128->32->8->1, group max ----------------
template <int F32>
__global__ __launch_bounds__(256) void k_ent(
    const void* __restrict__ entity, const void* __restrict__ ew1, const void* __restrict__ eb1,
    const void* __restrict__ ew2, const void* __restrict__ eb2,
    const void* __restrict__ ew3, const void* __restrict__ eb3,
    unsigned* __restrict__ egws, const unsigned* __restrict__ flag) {
  if (*flag != (unsigned)F32) return;
  __shared__ __align__(16) u16 xl[32 * 136];
  __shared__ __align__(16) u16 w1l[32 * 136];
  __shared__ float h1l[32 * 33];
  __shared__ float h2l[32 * 9];
  const int t = threadIdx.x;
  const int row0 = blockIdx.x * 32;
#pragma unroll
  for (int p = 0; p < 2; ++p) {
    int lin = p * 256 + t, rr = lin >> 4, cc = lin & 15;
    *(s16x8*)(xl + rr * 136 + cc * 8) =
        load8b<F32>(entity, (size_t)(row0 + rr) * 128 + cc * 8);
    *(s16x8*)(w1l + rr * 136 + cc * 8) = load8b<F32>(ew1, (size_t)rr * 128 + cc * 8);
  }
  __syncthreads();
  {  // layer1
    const int r = t >> 3, g = t & 7;
    float acc[4] = {0.f, 0.f, 0.f, 0.f};
#pragma unroll 4
    for (int c = 0; c < 16; ++c) {
      s16x8 xv = *(const s16x8*)(xl + r * 136 + c * 8);
      float xf[8];
#pragma unroll
      for (int j = 0; j < 8; ++j) xf[j] = bf2f((u16)xv[j]);
#pragma unroll
      for (int s = 0; s < 4; ++s) {
        s16x8 wv = *(const s16x8*)(w1l + (g + 8 * s) * 136 + c * 8);
#pragma unroll
        for (int j = 0; j < 8; ++j) acc[s] += xf[j] * bf2f((u16)wv[j]);
      }
    }
#pragma unroll
    for (int s = 0; s < 4; ++s)
      h1l[r * 33 + g + 8 * s] = relu(acc[s] + ld1<F32>(eb1, g + 8 * s));
  }
  __syncthreads();
  {  // layer2
    const int r = t >> 3, o = t & 7;
    float a = ld1<F32>(eb2, o);
#pragma unroll 8
    for (int k = 0; k < 32; ++k) a += h1l[r * 33 + k] * ld1<F32>(ew2, o * 32 + k);
    h2l[r * 9 + o] = relu(a);
  }
  __syncthreads();
  if (t < 32) {  // layer3 + type + group max
    float s = ld1<F32>(eb3, 0);
#pragma unroll
    for (int k = 0; k < 8; ++k) s += h2l[t * 9 + k] * ld1<F32>(ew3, k);
    int ty = 0;
#pragma unroll
    for (int c = 0; c < 8; ++c) {
      s16x8 v = *(const s16x8*)(xl + t * 136 + c * 8);
#pragma unroll
      for (int j = 0; j < 8; ++j)
        if ((u16)v[j] == (u16)0x3F80) ty = c * 8 + j;
    }
    atomicMax(egws + ty, encf(s));
  }
}

// ---------------- target encoder layer1 partials ----------------
template <int F32>
__global__ __launch_bounds__(256) void k_tgt(const void* __restrict__ target,
                                             const void* __restrict__ tw1,
                                             float* __restrict__ tpart,
                                             const unsigned* __restrict__ flag) {
  if (*flag != (unsigned)F32) return;
  __shared__ float red[256];
  const int t = threadIdx.x;
  const int o = blockIdx.x >> 2, c = blockIdx.x & 3;
  float a = 0.f;
  for (int i = t; i < 2116; i += 256) {
    float xf[8], wf[8];
    loadf8<F32>(target, (size_t)c * 16928 + i * 8, xf);
    loadf8<F32>(tw1, (size_t)o * 67712 + c * 16928 + i * 8, wf);
#pragma unroll
    for (int j = 0; j < 8; ++j) a += xf[j] * wf[j];
  }
  red[t] = a;
  __syncthreads();
  for (int st = 128; st > 0; st >>= 1) {
    if (t < st) red[t] += red[t + st];
    __syncthreads();
  }
  if (t == 0) atomicAdd(tpart + o, red[0]);
}

// ---------------- relationship encoder (bf16 fallback path, original) ----------------
#define RK 2240
template <int F32>
__global__ __launch_bounds__(256) void k_rel(
    const void* __restrict__ rel, const void* __restrict__ rw1, const void* __restrict__ rb1,
    const void* __restrict__ rw2, const void* __restrict__ rb2,
    const void* __restrict__ rw3, const void* __restrict__ rb3,
    const void* __restrict__ rw4, const void* __restrict__ rb4,
    const void* __restrict__ rw5, const void* __restrict__ rb5,
    unsigned* __restrict__ rgws, const unsigned* __restrict__ flag) {
  if (*flag != (unsigned)F32) return;
  __shared__ __align__(16) unsigned char sm[53760];
  u16* smA = (u16*)sm;
  u16* smB = (u16*)(sm + 8192);
  u16* r0 = (u16*)sm;               // later h2 [128][72]
  u16* smRF = (u16*)(sm + 18432);   // rf1 [128][136]
  int* styp = (int*)(sm + 53248);

  const int t = threadIdx.x;
  const int lane = t & 63;
  const int wid = t >> 6;
  const int row0 = blockIdx.x * 128;
  const int fr = lane & 15, fq = lane >> 4;

  if (t < 128) {  // one-hot type scan, cols 0..127
    int ty = 0;
#pragma unroll 4
    for (int c = 0; c < 16; ++c) {
      s16x8 v = load8b<F32>(rel, (size_t)(row0 + t) * RK + c * 8);
#pragma unroll
      for (int j = 0; j < 8; ++j)
        if ((u16)v[j] == (u16)0x3F80) ty = c * 8 + j;
    }
    styp[t] = ty;
  }

  // ---- layer1: C[128][128] = rel_tile @ rw1^T, K=2240 ----
  const int wm = wid >> 1, wn = wid & 1;
  f32x4 acc[4][4];
#pragma unroll
  for (int i = 0; i < 4; ++i)
#pragma unroll
    for (int j = 0; j < 4; ++j) acc[i][j] = f32x4{0.f, 0.f, 0.f, 0.f};

  const size_t gA0 = (size_t)(row0 + (t >> 2)) * RK + (t & 3) * 8;
  const size_t gB0 = (size_t)(t >> 2) * RK + (t & 3) * 8;

  for (int ki = 0; ki < 70; ++ki) {
    const int k0 = ki * 32;
    s16x8 va0 = load8b<F32>(rel, gA0 + k0);
    s16x8 va1 = load8b<F32>(rel, gA0 + (size_t)64 * RK + k0);
    s16x8 vb0 = load8b<F32>(rw1, gB0 + k0);
    s16x8 vb1 = load8b<F32>(rw1, gB0 + (size_t)64 * RK + k0);
    __syncthreads();
    *(s16x8*)(smA + t * 8) = va0;
    *(s16x8*)(smA + 2048 + t * 8) = va1;
    *(s16x8*)(smB + t * 8) = vb0;
    *(s16x8*)(smB + 2048 + t * 8) = vb1;
    __syncthreads();
    s16x8 a[4], b[4];
#pragma unroll
    for (int i = 0; i < 4; ++i)
      a[i] = *(const s16x8*)(smA + (wm * 64 + i * 16 + fr) * 32 + fq * 8);
#pragma unroll
    for (int j = 0; j < 4; ++j)
      b[j] = *(const s16x8*)(smB + (wn * 64 + j * 16 + fr) * 32 + fq * 8);
#pragma unroll
    for (int i = 0; i < 4; ++i)
#pragma unroll
      for (int j = 0; j < 4; ++j) acc[i][j] = mfma16(a[i], b[j], acc[i][j]);
  }
  __syncthreads();

  // epilogue L1 -> smRF[128][136] bf16
#pragma unroll
  for (int j = 0; j < 4; ++j) {
    const int col = wn * 64 + j * 16 + fr;
    const float bias = ld1<F32>(rb1, col);
#pragma unroll
    for (int i = 0; i < 4; ++i) {
      const int rbase = wm * 64 + i * 16 + fq * 4;
#pragma unroll
      for (int r = 0; r < 4; ++r)
        smRF[(rbase + r) * 136 + col] = f2bf(relu(acc[i][j][r] + bias));
    }
  }
  __syncthreads();

  // ---- layers 2-5: VALU, thread t owns row t ----
  if (t < 128) {
    const u16* rfrow = smRF + t * 136;
    for (int o = 0; o < 64; ++o) {
      float a = ld1<F32>(rb2, o);
      for (int k = 0; k < 128; k += 8) {
        float wf[8];
        loadf8<F32>(rw2, o * 128 + k, wf);
#pragma unroll
        for (int j = 0; j < 8; ++j) a += bf2f(rfrow[k + j]) * wf[j];
      }
      r0[t * 72 + o] = f2bf(relu(a));
    }
    const u16* h2row = r0 + t * 72;
    float h3[32];
#pragma unroll
    for (int o = 0; o < 32; ++o) {
      float a = ld1<F32>(rb3, o);
      for (int k = 0; k < 64; k += 8) {
        float wf[8];
        loadf8<F32>(rw3, o * 64 + k, wf);
#pragma unroll
        for (int j = 0; j < 8; ++j) a += bf2f(h2row[k + j]) * wf[j];
      }
      h3[o] = relu(a);
    }
    float h4[8];
#pragma unroll
    for (int o = 0; o < 8; ++o) {
      float a = ld1<F32>(rb4, o);
#pragma unroll
      for (int k = 0; k < 32; ++k) a += h3[k] * ld1<F32>(rw4, o * 32 + k);
      h4[o] = relu(a);
    }
    float s = ld1<F32>(rb5, 0);
#pragma unroll
    for (int k = 0; k < 8; ++k) s += h4[k] * ld1<F32>(rw5, k);
    atomicMax(rgws + styp[t], encf(s));
  }
}

// ---------------- relationship encoder, f32 fast path ----------------
// Register-direct MFMA: each wave loads its own A/B fragments straight from
// global (f32x4 pairs), converts f32->bf16 in regs with the SAME f2bf as the
// validated k_rel<1> (bit-identical layer1), zero LDS / zero barriers in the
// main loop. B (rw1, 1.15 MB) is L2-resident. Tail layers copied verbatim.
__global__ __launch_bounds__(256, 2) void k_relf(
    const float* __restrict__ rel, const float* __restrict__ rw1, const float* __restrict__ rb1,
    const float* __restrict__ rw2, const float* __restrict__ rb2,
    const float* __restrict__ rw3, const float* __restrict__ rb3,
    const float* __restrict__ rw4, const float* __restrict__ rb4,
    const float* __restrict__ rw5, const float* __restrict__ rb5,
    unsigned* __restrict__ rgws, const unsigned* __restrict__ flag) {
  if (*flag != 1u) return;
  __shared__ __align__(16) unsigned char sm[53760];
  u16* r0 = (u16*)sm;              // h2 [128][72]
  u16* smRF = (u16*)(sm + 18432);  // rf1 [128][136]

  const int t = threadIdx.x;
  const int lane = t & 63;
  const int wid = t >> 6;
  const int row0 = blockIdx.x * 128;
  const int fr = lane & 15, fq = lane >> 4;
  const int wm = wid >> 1, wn = wid & 1;

  // one-hot type scan (cols 0..127 of own row); result stays in register —
  // the same thread (t<128) runs the tail for row t.
  int ty = 0;
  if (t < 128) {
    const float* rrow = rel + (size_t)(row0 + t) * RK;
#pragma unroll 8
    for (int c = 0; c < 128; c += 4) {
      f32x4 v = *(const f32x4*)(rrow + c);
#pragma unroll
      for (int j = 0; j < 4; ++j)
        if (v[j] == 1.0f) ty = c + j;
    }
  }

  // ---- layer1: C[128][128] = rel_tile @ rw1^T, K=2240, reg-direct ----
  f32x4 acc[4][4];
#pragma unroll
  for (int i = 0; i < 4; ++i)
#pragma unroll
    for (int j = 0; j < 4; ++j) acc[i][j] = f32x4{0.f, 0.f, 0.f, 0.f};

  const float* pa[4];
  const float* pb[4];
#pragma unroll
  for (int i = 0; i < 4; ++i) {
    pa[i] = rel + (size_t)(row0 + wm * 64 + i * 16 + fr) * RK + fq * 8;
    pb[i] = rw1 + (size_t)(wn * 64 + i * 16 + fr) * RK + fq * 8;
  }

#pragma unroll 2
  for (int ki = 0; ki < 70; ++ki) {
    f32x4 ar[4][2], br[4][2];
#pragma unroll
    for (int i = 0; i < 4; ++i) {
      ar[i][0] = *(const f32x4*)pa[i];
      ar[i][1] = *(const f32x4*)(pa[i] + 4);
      br[i][0] = *(const f32x4*)pb[i];
      br[i][1] = *(const f32x4*)(pb[i] + 4);
      pa[i] += 32;
      pb[i] += 32;
    }
    s16x8 af[4], bg[4];
#pragma unroll
    for (int i = 0; i < 4; ++i) {
#pragma unroll
      for (int e = 0; e < 4; ++e) {
        af[i][e] = (short)f2bf(ar[i][0][e]);
        af[i][4 + e] = (short)f2bf(ar[i][1][e]);
        bg[i][e] = (short)f2bf(br[i][0][e]);
        bg[i][4 + e] = (short)f2bf(br[i][1][e]);
      }
    }
#pragma unroll
    for (int i = 0; i < 4; ++i)
#pragma unroll
      for (int j = 0; j < 4; ++j) acc[i][j] = mfma16(af[i], bg[j], acc[i][j]);
  }

  // epilogue L1 -> smRF[128][136] bf16
#pragma unroll
  for (int j = 0; j < 4; ++j) {
    const int col = wn * 64 + j * 16 + fr;
    const float bias = rb1[col];
#pragma unroll
    for (int i = 0; i < 4; ++i) {
      const int rbase = wm * 64 + i * 16 + fq * 4;
#pragma unroll
      for (int r = 0; r < 4; ++r)
        smRF[(rbase + r) * 136 + col] = f2bf(relu(acc[i][j][r] + bias));
    }
  }
  __syncthreads();

  // ---- layers 2-5: VALU, thread t owns row t (verbatim from k_rel<1>) ----
  if (t < 128) {
    const u16* rfrow = smRF + t * 136;
    for (int o = 0; o < 64; ++o) {
      float a = rb2[o];
      for (int k = 0; k < 128; k += 8) {
        f32x4 w0 = *(const f32x4*)(rw2 + o * 128 + k);
        f32x4 w1 = *(const f32x4*)(rw2 + o * 128 + k + 4);
#pragma unroll
        for (int j = 0; j < 4; ++j) {
          a += bf2f(rfrow[k + j]) * w0[j];
          a += bf2f(rfrow[k + 4 + j]) * w1[j];
        }
      }
      r0[t * 72 + o] = f2bf(relu(a));
    }
    const u16* h2row = r0 + t * 72;
    float h3[32];
#pragma unroll
    for (int o = 0; o < 32; ++o) {
      float a = rb3[o];
      for (int k = 0; k < 64; k += 8) {
        f32x4 w0 = *(const f32x4*)(rw3 + o * 64 + k);
        f32x4 w1 = *(const f32x4*)(rw3 + o * 64 + k + 4);
#pragma unroll
        for (int j = 0; j < 4; ++j) {
          a += bf2f(h2row[k + j]) * w0[j];
          a += bf2f(h2row[k + 4 + j]) * w1[j];
        }
      }
      h3[o] = relu(a);
    }
    float h4[8];
#pragma unroll
    for (int o = 0; o < 8; ++o) {
      float a = rb4[o];
#pragma unroll
      for (int k = 0; k < 32; ++k) a += h3[k] * rw4[o * 32 + k];
      h4[o] = relu(a);
    }
    float s = rb5[0];
#pragma unroll
    for (int k = 0; k < 8; ++k) s += h4[k] * rw5[k];
    atomicMax(rgws + ty, encf(s));
  }
}

// ---------------- finale ----------------
template <int F32>
__global__ __launch_bounds__(256) void k_fin(
    const unsigned* __restrict__ egws, const unsigned* __restrict__ rgws,
    const float* __restrict__ tpart, const void* __restrict__ tb1,
    const void* __restrict__ tw2, const void* __restrict__ tb2,
    const void* __restrict__ wih, const void* __restrict__ whh,
    const void* __restrict__ bih, const void* __restrict__ bhh,
    const void* __restrict__ hidden, const void* __restrict__ aw,
    const void* __restrict__ ab, const void* __restrict__ amask,
    void* __restrict__ outp, const unsigned* __restrict__ flag) {
  if (*flag != (unsigned)F32) return;
  __shared__ float env[208];
  __shared__ float th1[64];
  __shared__ float gx[384], gh[384];
  __shared__ float hv[128], hid[128];
  __shared__ float red[256];
  const int t = threadIdx.x;
  if (t < 64) {
    unsigned e = egws[t];
    env[t] = e ? decf(e) : 0.f;
    th1[t] = relu(tpart[t] + ld1<F32>(tb1, t));
  }
  if (t >= 64 && t < 192) {
    unsigned e = rgws[t - 64];
    env[t] = e ? decf(e) : 0.f;
  }
  if (t < 128) hid[t] = ld1<F32>(hidden, t);
  __syncthreads();
  if (t < 16) {
    float a = ld1<F32>(tb2, t);
    for (int k = 0; k < 64; k += 8) {
      float wf[8];
      loadf8<F32>(tw2, t * 64 + k, wf);
#pragma unroll
      for (int j = 0; j < 8; ++j) a += th1[k + j] * wf[j];
    }
    env[192 + t] = a;
  }
  __syncthreads();
  for (int o = t; o < 384; o += 256) {
    float ax = ld1<F32>(bih, o);
#pragma unroll 2
    for (int c = 0; c < 26; ++c) {
      float wf[8];
      loadf8<F32>(wih, (size_t)o * 208 + c * 8, wf);
#pragma unroll
      for (int j = 0; j < 8; ++j) ax += env[c * 8 + j] * wf[j];
    }
    gx[o] = ax;
    float ah = ld1<F32>(bhh, o);
#pragma unroll 2
    for (int c = 0; c < 16; ++c) {
      float wf[8];
      loadf8<F32>(whh, (size_t)o * 128 + c * 8, wf);
#pragma unroll
      for (int j = 0; j < 8; ++j) ah += hid[c * 8 + j] * wf[j];
    }
    gh[o] = ah;
  }
  __syncthreads();
  if (t < 128) {
    float r = 1.f / (1.f + expf(-(gx[t] + gh[t])));
    float z = 1.f / (1.f + expf(-(gx[128 + t] + gh[128 + t])));
    float n = tanhf(gx[256 + t] + r * gh[256 + t]);
    hv[t] = (1.f - z) * n + z * hid[t];
  }
  __syncthreads();
  float s = ld1<F32>(ab, t);
#pragma unroll 4
  for (int c = 0; c < 16; ++c) {
    float wf[8];
    loadf8<F32>(aw, (size_t)t * 128 + c * 8, wf);
#pragma unroll
    for (int j = 0; j < 8; ++j) s += hv[c * 8 + j] * wf[j];
  }
  red[t] = s;
  __syncthreads();
  for (int st = 128; st > 0; st >>= 1) {
    if (t < st) red[t] = fmaxf(red[t], red[t + st]);
    __syncthreads();
  }
  float m = red[0];
  __syncthreads();
  float e = expf(s - m);
  red[t] = e;
  __syncthreads();
  for (int st = 128; st > 0; st >>= 1) {
    if (t < st) red[t] += red[t + st];
    __syncthreads();
  }
  float v = e * (1.f / red[0]) * ld1<F32>(amask, t);
  if (F32) ((float*)outp)[t] = v;
  else ((u16*)outp)[t] = f2bf(v);
}

extern "C" void kernel_launch(void* const* d_in, const int* in_sizes, int n_in,
                              void* d_out, int out_size, void* d_ws, size_t ws_size,
                              hipStream_t stream) {
  const void* entity = d_in[0];
  const void* rel    = d_in[1];
  const void* target = d_in[2];
  const void* amask  = d_in[3];
  const void* ew1 = d_in[4];  const void* eb1 = d_in[5];
  const void* ew2 = d_in[6];  const void* eb2 = d_in[7];
  const void* ew3 = d_in[8];  const void* eb3 = d_in[9];
  const void* rw1 = d_in[10]; const void* rb1 = d_in[11];
  const void* rw2 = d_in[12]; const void* rb2 = d_in[13];
  const void* rw3 = d_in[14]; const void* rb3 = d_in[15];
  const void* rw4 = d_in[16]; const void* rb4 = d_in[17];
  const void* rw5 = d_in[18]; const void* rb5 = d_in[19];
  const void* tw1 = d_in[20]; const void* tb1 = d_in[21];
  const void* tw2 = d_in[22]; const void* tb2 = d_in[23];
  const void* wih = d_in[24]; const void* whh = d_in[25];
  const void* bih = d_in[26]; const void* bhh = d_in[27];
  const void* hidden = d_in[28];
  const void* aw = d_in[29];  const void* ab = d_in[30];

  unsigned* ws = (unsigned*)d_ws;
  unsigned* egws = ws;                // [64]
  unsigned* rgws = ws + 64;           // [128]
  float* tpart = (float*)(ws + 192);  // [64]
  const unsigned* flag = ws + 256;    // [1]: 1 = f32 inputs

  hipLaunchKernelGGL(k_detect, dim3(1), dim3(256), 0, stream,
                     (const u16*)entity, (const u16*)rel, ws);

  hipLaunchKernelGGL((k_ent<0>), dim3(64), dim3(256), 0, stream,
                     entity, ew1, eb1, ew2, eb2, ew3, eb3, egws, flag);
  hipLaunchKernelGGL((k_ent<1>), dim3(64), dim3(256), 0, stream,
                     entity, ew1, eb1, ew2, eb2, ew3, eb3, egws, flag);

  hipLaunchKernelGGL((k_tgt<0>), dim3(256), dim3(256), 0, stream, target, tw1, tpart, flag);
  hipLaunchKernelGGL((k_tgt<1>), dim3(256), dim3(256), 0, stream, target, tw1, tpart, flag);

  hipLaunchKernelGGL((k_rel<0>), dim3(512), dim3(256), 0, stream,
                     rel, rw1, rb1, rw2, rb2, rw3, rb3, rw4, rb4, rw5, rb5, rgws, flag);
  hipLaunchKernelGGL(k_relf, dim3(512), dim3(256), 0, stream,
                     (const float*)rel, (const float*)rw1, (const float*)rb1,
                     (const float*)rw2, (const float*)rb2, (const float*)rw3,
                     (const float*)rb3, (const float*)rw4, (const float*)rb4,
                     (const float*)rw5, (const float*)rb5, rgws, flag);

  hipLaunchKernelGGL((k_fin<0>), dim3(1), dim3(256), 0, stream,
                     egws, rgws, tpart, tb1, tw2, tb2, wih, whh, bih, bhh,
                     hidden, aw, ab, amask, d_out, flag);
  hipLaunchKernelGGL((k_fin<1>), dim3(1), dim3(256), 0, stream,
                     egws, rgws, tpart, tb1, tw2, tb2, wih, whh, bih, bhh,
                     hidden, aw, ab, amask, d_out, flag);
}

// Round 3
// 1102.394 us; speedup vs baseline: 1.1672x; 1.1672x over previous
//
#include <hip/hip_runtime.h>
#include <stdint.h>

typedef unsigned short u16;
typedef short s16x8 __attribute__((ext_vector_type(8)));
typedef float f32x4 __attribute__((ext_vector_type(4)));

__device__ __forceinline__ float bf2f(u16 u) {
  union { unsigned u; float f; } c; c.u = ((unsigned)u) << 16; return c.f;
}
__device__ __forceinline__ u16 f2bf(float f) {
  union { float f; unsigned u; } c; c.f = f;
  unsigned r = c.u + 0x7FFFu + ((c.u >> 16) & 1u);
  return (u16)(r >> 16);
}
__device__ __forceinline__ unsigned encf(float x) {
  union { float f; unsigned u; } c; c.f = x;
  return (c.u & 0x80000000u) ? ~c.u : (c.u | 0x80000000u);
}
__device__ __forceinline__ float decf(unsigned e) {
  union { unsigned u; float f; } c;
  c.u = (e & 0x80000000u) ? (e ^ 0x80000000u) : ~e;
  return c.f;
}
__device__ __forceinline__ f32x4 mfma16(s16x8 a, s16x8 b, f32x4 c) {
  return __builtin_amdgcn_mfma_f32_16x16x32_bf16(a, b, c, 0, 0, 0);
}
__device__ __forceinline__ float relu(float x) { return x > 0.f ? x : 0.f; }
__device__ __forceinline__ s16x8 cvt8(f32x4 a, f32x4 b) {
  s16x8 r;
#pragma unroll
  for (int e = 0; e < 4; ++e) {
    r[e] = (short)f2bf(a[e]);
    r[4 + e] = (short)f2bf(b[e]);
  }
  return r;
}

// ---- dtype-generic loaders: element index ei, F32 selects f32 vs bf16 buffers ----
template <int F32>
__device__ __forceinline__ void loadf8(const void* p, size_t ei, float* o) {
  if (F32) {
    const float* f = (const float*)p + ei;
    f32x4 a = *(const f32x4*)f;
    f32x4 b = *(const f32x4*)(f + 4);
#pragma unroll
    for (int j = 0; j < 4; ++j) { o[j] = a[j]; o[4 + j] = b[j]; }
  } else {
    s16x8 v = *(const s16x8*)((const u16*)p + ei);
#pragma unroll
    for (int j = 0; j < 8; ++j) o[j] = bf2f((u16)v[j]);
  }
}
template <int F32>
__device__ __forceinline__ s16x8 load8b(const void* p, size_t ei) {  // -> 8 bf16
  if (F32) {
    float o[8]; loadf8<1>(p, ei, o);
    s16x8 r;
#pragma unroll
    for (int j = 0; j < 8; ++j) r[j] = (short)f2bf(o[j]);
    return r;
  } else {
    return *(const s16x8*)((const u16*)p + ei);
  }
}
template <int F32>
__device__ __forceinline__ float ld1(const void* p, size_t ei) {
  return F32 ? ((const float*)p)[ei] : bf2f(((const u16*)p)[ei]);
}

// ---------------- detect dtype + init ws ----------------
// ws (u32): [0:64) egws, [64:192) rgws, [192:256) tpart, [256] flag (1 = f32)
__global__ void k_detect(const u16* __restrict__ entity, const u16* __restrict__ rel,
                         unsigned* __restrict__ ws) {
  __shared__ unsigned cnt[256];
  const int t = threadIdx.x;
  ws[t] = 0u;
  unsigned c = 0;
  for (int i = t; i < 16384; i += 256) {
    unsigned u = rel[i];
    if ((u & 0x7F80u) == 0x7F80u) ++c;  // exp all-ones: impossible in genuine bf16 data
  }
  for (int i = t; i < 8192; i += 256) {
    unsigned u = entity[i];
    if ((u & 0x7F80u) == 0x7F80u) ++c;
  }
  cnt[t] = c;
  __syncthreads();
  for (int st = 128; st > 0; st >>= 1) {
    if (t < st) cnt[t] += cnt[t + st];
    __syncthreads();
  }
  if (t == 0) ws[256] = cnt[0] ? 1u : 0u;
}

// ---------------- entity encoder: 2048 rows, 128->32->8->1, group max ----------------
template <int F32>
__global__ __launch_bounds__(256) void k_ent(
    const void* __restrict__ entity, const void* __restrict__ ew1, const void* __restrict__ eb1,
    const void* __restrict__ ew2, const void* __restrict__ eb2,
    const void* __restrict__ ew3, const void* __restrict__ eb3,
    unsigned* __restrict__ egws, const unsigned* __restrict__ flag) {
  if (*flag != (unsigned)F32) return;
  __shared__ __align__(16) u16 xl[32 * 136];
  __shared__ __align__(16) u16 w1l[32 * 136];
  __shared__ float h1l[32 * 33];
  __shared__ float h2l[32 * 9];
  const int t = threadIdx.x;
  const int row0 = blockIdx.x * 32;
#pragma unroll
  for (int p = 0; p < 2; ++p) {
    int lin = p * 256 + t, rr = lin >> 4, cc = lin & 15;
    *(s16x8*)(xl + rr * 136 + cc * 8) =
        load8b<F32>(entity, (size_t)(row0 + rr) * 128 + cc * 8);
    *(s16x8*)(w1l + rr * 136 + cc * 8) = load8b<F32>(ew1, (size_t)rr * 128 + cc * 8);
  }
  __syncthreads();
  {  // layer1
    const int r = t >> 3, g = t & 7;
    float acc[4] = {0.f, 0.f, 0.f, 0.f};
#pragma unroll 4
    for (int c = 0; c < 16; ++c) {
      s16x8 xv = *(const s16x8*)(xl + r * 136 + c * 8);
      float xf[8];
#pragma unroll
      for (int j = 0; j < 8; ++j) xf[j] = bf2f((u16)xv[j]);
#pragma unroll
      for (int s = 0; s < 4; ++s) {
        s16x8 wv = *(const s16x8*)(w1l + (g + 8 * s) * 136 + c * 8);
#pragma unroll
        for (int j = 0; j < 8; ++j) acc[s] += xf[j] * bf2f((u16)wv[j]);
      }
    }
#pragma unroll
    for (int s = 0; s < 4; ++s)
      h1l[r * 33 + g + 8 * s] = relu(acc[s] + ld1<F32>(eb1, g + 8 * s));
  }
  __syncthreads();
  {  // layer2
    const int r = t >> 3, o = t & 7;
    float a = ld1<F32>(eb2, o);
#pragma unroll 8
    for (int k = 0; k < 32; ++k) a += h1l[r * 33 + k] * ld1<F32>(ew2, o * 32 + k);
    h2l[r * 9 + o] = relu(a);
  }
  __syncthreads();
  if (t < 32) {  // layer3 + type + group max
    float s = ld1<F32>(eb3, 0);
#pragma unroll
    for (int k = 0; k < 8; ++k) s += h2l[t * 9 + k] * ld1<F32>(ew3, k);
    int ty = 0;
#pragma unroll
    for (int c = 0; c < 8; ++c) {
      s16x8 v = *(const s16x8*)(xl + t * 136 + c * 8);
#pragma unroll
      for (int j = 0; j < 8; ++j)
        if ((u16)v[j] == (u16)0x3F80) ty = c * 8 + j;
    }
    atomicMax(egws + ty, encf(s));
  }
}

// ---------------- target encoder layer1 partials ----------------
template <int F32>
__global__ __launch_bounds__(256) void k_tgt(const void* __restrict__ target,
                                             const void* __restrict__ tw1,
                                             float* __restrict__ tpart,
                                             const unsigned* __restrict__ flag) {
  if (*flag != (unsigned)F32) return;
  __shared__ float red[256];
  const int t = threadIdx.x;
  const int o = blockIdx.x >> 2, c = blockIdx.x & 3;
  float a = 0.f;
  for (int i = t; i < 2116; i += 256) {
    float xf[8], wf[8];
    loadf8<F32>(target, (size_t)c * 16928 + i * 8, xf);
    loadf8<F32>(tw1, (size_t)o * 67712 + c * 16928 + i * 8, wf);
#pragma unroll
    for (int j = 0; j < 8; ++j) a += xf[j] * wf[j];
  }
  red[t] = a;
  __syncthreads();
  for (int st = 128; st > 0; st >>= 1) {
    if (t < st) red[t] += red[t + st];
    __syncthreads();
  }
  if (t == 0) atomicAdd(tpart + o, red[0]);
}

// ---------------- relationship encoder (bf16 fallback path, original) ----------------
#define RK 2240
template <int F32>
__global__ __launch_bounds__(256) void k_rel(
    const void* __restrict__ rel, const void* __restrict__ rw1, const void* __restrict__ rb1,
    const void* __restrict__ rw2, const void* __restrict__ rb2,
    const void* __restrict__ rw3, const void* __restrict__ rb3,
    const void* __restrict__ rw4, const void* __restrict__ rb4,
    const void* __restrict__ rw5, const void* __restrict__ rb5,
    unsigned* __restrict__ rgws, const unsigned* __restrict__ flag) {
  if (*flag != (unsigned)F32) return;
  __shared__ __align__(16) unsigned char sm[53760];
  u16* smA = (u16*)sm;
  u16* smB = (u16*)(sm + 8192);
  u16* r0 = (u16*)sm;               // later h2 [128][72]
  u16* smRF = (u16*)(sm + 18432);   // rf1 [128][136]
  int* styp = (int*)(sm + 53248);

  const int t = threadIdx.x;
  const int lane = t & 63;
  const int wid = t >> 6;
  const int row0 = blockIdx.x * 128;
  const int fr = lane & 15, fq = lane >> 4;

  if (t < 128) {  // one-hot type scan, cols 0..127
    int ty = 0;
#pragma unroll 4
    for (int c = 0; c < 16; ++c) {
      s16x8 v = load8b<F32>(rel, (size_t)(row0 + t) * RK + c * 8);
#pragma unroll
      for (int j = 0; j < 8; ++j)
        if ((u16)v[j] == (u16)0x3F80) ty = c * 8 + j;
    }
    styp[t] = ty;
  }

  // ---- layer1: C[128][128] = rel_tile @ rw1^T, K=2240 ----
  const int wm = wid >> 1, wn = wid & 1;
  f32x4 acc[4][4];
#pragma unroll
  for (int i = 0; i < 4; ++i)
#pragma unroll
    for (int j = 0; j < 4; ++j) acc[i][j] = f32x4{0.f, 0.f, 0.f, 0.f};

  const size_t gA0 = (size_t)(row0 + (t >> 2)) * RK + (t & 3) * 8;
  const size_t gB0 = (size_t)(t >> 2) * RK + (t & 3) * 8;

  for (int ki = 0; ki < 70; ++ki) {
    const int k0 = ki * 32;
    s16x8 va0 = load8b<F32>(rel, gA0 + k0);
    s16x8 va1 = load8b<F32>(rel, gA0 + (size_t)64 * RK + k0);
    s16x8 vb0 = load8b<F32>(rw1, gB0 + k0);
    s16x8 vb1 = load8b<F32>(rw1, gB0 + (size_t)64 * RK + k0);
    __syncthreads();
    *(s16x8*)(smA + t * 8) = va0;
    *(s16x8*)(smA + 2048 + t * 8) = va1;
    *(s16x8*)(smB + t * 8) = vb0;
    *(s16x8*)(smB + 2048 + t * 8) = vb1;
    __syncthreads();
    s16x8 a[4], b[4];
#pragma unroll
    for (int i = 0; i < 4; ++i)
      a[i] = *(const s16x8*)(smA + (wm * 64 + i * 16 + fr) * 32 + fq * 8);
#pragma unroll
    for (int j = 0; j < 4; ++j)
      b[j] = *(const s16x8*)(smB + (wn * 64 + j * 16 + fr) * 32 + fq * 8);
#pragma unroll
    for (int i = 0; i < 4; ++i)
#pragma unroll
      for (int j = 0; j < 4; ++j) acc[i][j] = mfma16(a[i], b[j], acc[i][j]);
  }
  __syncthreads();

  // epilogue L1 -> smRF[128][136] bf16
#pragma unroll
  for (int j = 0; j < 4; ++j) {
    const int col = wn * 64 + j * 16 + fr;
    const float bias = ld1<F32>(rb1, col);
#pragma unroll
    for (int i = 0; i < 4; ++i) {
      const int rbase = wm * 64 + i * 16 + fq * 4;
#pragma unroll
      for (int r = 0; r < 4; ++r)
        smRF[(rbase + r) * 136 + col] = f2bf(relu(acc[i][j][r] + bias));
    }
  }
  __syncthreads();

  // ---- layers 2-5: VALU, thread t owns row t ----
  if (t < 128) {
    const u16* rfrow = smRF + t * 136;
    for (int o = 0; o < 64; ++o) {
      float a = ld1<F32>(rb2, o);
      for (int k = 0; k < 128; k += 8) {
        float wf[8];
        loadf8<F32>(rw2, o * 128 + k, wf);
#pragma unroll
        for (int j = 0; j < 8; ++j) a += bf2f(rfrow[k + j]) * wf[j];
      }
      r0[t * 72 + o] = f2bf(relu(a));
    }
    const u16* h2row = r0 + t * 72;
    float h3[32];
#pragma unroll
    for (int o = 0; o < 32; ++o) {
      float a = ld1<F32>(rb3, o);
      for (int k = 0; k < 64; k += 8) {
        float wf[8];
        loadf8<F32>(rw3, o * 64 + k, wf);
#pragma unroll
        for (int j = 0; j < 8; ++j) a += bf2f(h2row[k + j]) * wf[j];
      }
      h3[o] = relu(a);
    }
    float h4[8];
#pragma unroll
    for (int o = 0; o < 8; ++o) {
      float a = ld1<F32>(rb4, o);
#pragma unroll
      for (int k = 0; k < 32; ++k) a += h3[k] * ld1<F32>(rw4, o * 32 + k);
      h4[o] = relu(a);
    }
    float s = ld1<F32>(rb5, 0);
#pragma unroll
    for (int k = 0; k < 8; ++k) s += h4[k] * ld1<F32>(rw5, k);
    atomicMax(rgws + styp[t], encf(s));
  }
}

// ---------------- relationship encoder, f32 fast path ----------------
// LDS-staged MFMA with depth-1 prefetch + ONE barrier per K-step:
//   step ki: issue 8x16B global loads for tile ki+1 into regs ->
//            ds_read frags of tile ki + 16 MFMA ->
//            cvt(f2bf) + ds_write tile ki+1 into the other buffer -> barrier.
// Numerics identical to validated k_rel<1>: f2bf at staging, same fragment
// layout, same 70-step MFMA order, same epilogue/tail arithmetic order.
// Type-scan reads the staged bf16 A-tile (steps 0..3), no global re-read.
__global__ __launch_bounds__(256, 2) void k_relg(
    const float* __restrict__ rel, const float* __restrict__ rw1, const float* __restrict__ rb1,
    const float* __restrict__ rw2, const float* __restrict__ rb2,
    const float* __restrict__ rw3, const float* __restrict__ rb3,
    const float* __restrict__ rw4, const float* __restrict__ rb4,
    const float* __restrict__ rw5, const float* __restrict__ rb5,
    unsigned* __restrict__ rgws, const unsigned* __restrict__ flag) {
  if (*flag != 1u) return;
  // LDS map: buf0A[8K]@0, buf0B[8K]@8192, buf1A[8K]@16384, buf1B[8K]@24576,
  // smRF[128][136]u16 @32768 (34816B, ends 67584). Tail h2 aliases @0 (18432B).
  __shared__ __align__(16) unsigned char sm[67584];
  const int t = threadIdx.x;
  const int lane = t & 63;
  const int wid = t >> 6;
  const int row0 = blockIdx.x * 128;
  const int fr = lane & 15, fq = lane >> 4;
  const int wm = wid >> 1, wn = wid & 1;

  // staging addresses: thread t stages row t>>1, 16-f32 half (t&1), both A and B
  const float* pA = rel + (size_t)(row0 + (t >> 1)) * RK + (t & 1) * 16;
  const float* pB = rw1 + (size_t)(t >> 1) * RK + (t & 1) * 16;
  const int sidx = 16 * t;  // u16 index into buf: (t>>1)*32 + (t&1)*16

  f32x4 acc[4][4];
#pragma unroll
  for (int i = 0; i < 4; ++i)
#pragma unroll
    for (int j = 0; j < 4; ++j) acc[i][j] = f32x4{0.f, 0.f, 0.f, 0.f};

  // prologue: stage tile 0 into buffer 0
  {
    f32x4 pre[8];
#pragma unroll
    for (int q = 0; q < 4; ++q) pre[q] = *(const f32x4*)(pA + q * 4);
#pragma unroll
    for (int q = 0; q < 4; ++q) pre[4 + q] = *(const f32x4*)(pB + q * 4);
    u16* dA = (u16*)sm;
    u16* dB = (u16*)(sm + 8192);
    *(s16x8*)(dA + sidx) = cvt8(pre[0], pre[1]);
    *(s16x8*)(dA + sidx + 8) = cvt8(pre[2], pre[3]);
    *(s16x8*)(dB + sidx) = cvt8(pre[4], pre[5]);
    *(s16x8*)(dB + sidx + 8) = cvt8(pre[6], pre[7]);
  }
  __syncthreads();

  int ty = 0;
#pragma unroll 1
  for (int ki = 0; ki < 70; ++ki) {
    const int nk = ki + 1;
    f32x4 pre[8];
    if (nk < 70) {  // issue next-tile loads (in flight across the MFMA phase)
      const int k0 = nk * 32;
#pragma unroll
      for (int q = 0; q < 4; ++q) pre[q] = *(const f32x4*)(pA + k0 + q * 4);
#pragma unroll
      for (int q = 0; q < 4; ++q) pre[4 + q] = *(const f32x4*)(pB + k0 + q * 4);
    }
    // compute from buf[ki&1]
    const u16* bA = (const u16*)(sm + (ki & 1) * 16384);
    const u16* bB = (const u16*)(sm + (ki & 1) * 16384 + 8192);
    s16x8 a[4], b[4];
#pragma unroll
    for (int i = 0; i < 4; ++i)
      a[i] = *(const s16x8*)(bA + (wm * 64 + i * 16 + fr) * 32 + fq * 8);
#pragma unroll
    for (int j = 0; j < 4; ++j)
      b[j] = *(const s16x8*)(bB + (wn * 64 + j * 16 + fr) * 32 + fq * 8);
#pragma unroll
    for (int i = 0; i < 4; ++i)
#pragma unroll
      for (int j = 0; j < 4; ++j) acc[i][j] = mfma16(a[i], b[j], acc[i][j]);
    if (ki < 4 && t < 128) {  // one-hot type scan from staged tile (cols ki*32..+32)
#pragma unroll
      for (int c = 0; c < 4; ++c) {
        s16x8 v = *(const s16x8*)(bA + t * 32 + c * 8);
#pragma unroll
        for (int j = 0; j < 8; ++j)
          if ((u16)v[j] == (u16)0x3F80) ty = ki * 32 + c * 8 + j;
      }
    }
    if (nk < 70) {  // convert + write next tile into the other buffer
      u16* dA = (u16*)(sm + (nk & 1) * 16384);
      u16* dB = (u16*)(sm + (nk & 1) * 16384 + 8192);
      *(s16x8*)(dA + sidx) = cvt8(pre[0], pre[1]);
      *(s16x8*)(dA + sidx + 8) = cvt8(pre[2], pre[3]);
      *(s16x8*)(dB + sidx) = cvt8(pre[4], pre[5]);
      *(s16x8*)(dB + sidx + 8) = cvt8(pre[6], pre[7]);
    }
    __syncthreads();  // writes of buf[nk&1] visible; reads of buf[ki&1] done
  }

  // ---- epilogue L1 -> smRF[128][136] bf16 ----
  u16* smRF = (u16*)(sm + 32768);
  u16* r0 = (u16*)sm;  // tail h2 [128][72], aliases staging buffers
#pragma unroll
  for (int j = 0; j < 4; ++j) {
    const int col = wn * 64 + j * 16 + fr;
    const float bias = rb1[col];
#pragma unroll
    for (int i = 0; i < 4; ++i) {
      const int rbase = wm * 64 + i * 16 + fq * 4;
#pragma unroll
      for (int r = 0; r < 4; ++r)
        smRF[(rbase + r) * 136 + col] = f2bf(relu(acc[i][j][r] + bias));
    }
  }
  __syncthreads();

  // ---- layers 2-5: VALU, thread t owns row t (original arithmetic order) ----
  if (t < 128) {
    const u16* rfrow = smRF + t * 136;
    for (int o = 0; o < 64; ++o) {
      float a = rb2[o];
      for (int k = 0; k < 128; k += 8) {
        float wf[8];
        loadf8<1>(rw2, (size_t)o * 128 + k, wf);
#pragma unroll
        for (int j = 0; j < 8; ++j) a += bf2f(rfrow[k + j]) * wf[j];
      }
      r0[t * 72 + o] = f2bf(relu(a));
    }
    const u16* h2row = r0 + t * 72;
    float h3[32];
#pragma unroll
    for (int o = 0; o < 32; ++o) {
      float a = rb3[o];
      for (int k = 0; k < 64; k += 8) {
        float wf[8];
        loadf8<1>(rw3, (size_t)o * 64 + k, wf);
#pragma unroll
        for (int j = 0; j < 8; ++j) a += bf2f(h2row[k + j]) * wf[j];
      }
      h3[o] = relu(a);
    }
    float h4[8];
#pragma unroll
    for (int o = 0; o < 8; ++o) {
      float a = rb4[o];
#pragma unroll
      for (int k = 0; k < 32; ++k) a += h3[k] * rw4[o * 32 + k];
      h4[o] = relu(a);
    }
    float s = rb5[0];
#pragma unroll
    for (int k = 0; k < 8; ++k) s += h4[k] * rw5[k];
    atomicMax(rgws + ty, encf(s));
  }
}

// ---------------- finale ----------------
template <int F32>
__global__ __launch_bounds__(256) void k_fin(
    const unsigned* __restrict__ egws, const unsigned* __restrict__ rgws,
    const float* __restrict__ tpart, const void* __restrict__ tb1,
    const void* __restrict__ tw2, const void* __restrict__ tb2,
    const void* __restrict__ wih, const void* __restrict__ whh,
    const void* __restrict__ bih, const void* __restrict__ bhh,
    const void* __restrict__ hidden, const void* __restrict__ aw,
    const void* __restrict__ ab, const void* __restrict__ amask,
    void* __restrict__ outp, const unsigned* __restrict__ flag) {
  if (*flag != (unsigned)F32) return;
  __shared__ float env[208];
  __shared__ float th1[64];
  __shared__ float gx[384], gh[384];
  __shared__ float hv[128], hid[128];
  __shared__ float red[256];
  const int t = threadIdx.x;
  if (t < 64) {
    unsigned e = egws[t];
    env[t] = e ? decf(e) : 0.f;
    th1[t] = relu(tpart[t] + ld1<F32>(tb1, t));
  }
  if (t >= 64 && t < 192) {
    unsigned e = rgws[t - 64];
    env[t] = e ? decf(e) : 0.f;
  }
  if (t < 128) hid[t] = ld1<F32>(hidden, t);
  __syncthreads();
  if (t < 16) {
    float a = ld1<F32>(tb2, t);
    for (int k = 0; k < 64; k += 8) {
      float wf[8];
      loadf8<F32>(tw2, t * 64 + k, wf);
#pragma unroll
      for (int j = 0; j < 8; ++j) a += th1[k + j] * wf[j];
    }
    env[192 + t] = a;
  }
  __syncthreads();
  for (int o = t; o < 384; o += 256) {
    float ax = ld1<F32>(bih, o);
#pragma unroll 2
    for (int c = 0; c < 26; ++c) {
      float wf[8];
      loadf8<F32>(wih, (size_t)o * 208 + c * 8, wf);
#pragma unroll
      for (int j = 0; j < 8; ++j) ax += env[c * 8 + j] * wf[j];
    }
    gx[o] = ax;
    float ah = ld1<F32>(bhh, o);
#pragma unroll 2
    for (int c = 0; c < 16; ++c) {
      float wf[8];
      loadf8<F32>(whh, (size_t)o * 128 + c * 8, wf);
#pragma unroll
      for (int j = 0; j < 8; ++j) ah += hid[c * 8 + j] * wf[j];
    }
    gh[o] = ah;
  }
  __syncthreads();
  if (t < 128) {
    float r = 1.f / (1.f + expf(-(gx[t] + gh[t])));
    float z = 1.f / (1.f + expf(-(gx[128 + t] + gh[128 + t])));
    float n = tanhf(gx[256 + t] + r * gh[256 + t]);
    hv[t] = (1.f - z) * n + z * hid[t];
  }
  __syncthreads();
  float s = ld1<F32>(ab, t);
#pragma unroll 4
  for (int c = 0; c < 16; ++c) {
    float wf[8];
    loadf8<F32>(aw, (size_t)t * 128 + c * 8, wf);
#pragma unroll
    for (int j = 0; j < 8; ++j) s += hv[c * 8 + j] * wf[j];
  }
  red[t] = s;
  __syncthreads();
  for (int st = 128; st > 0; st >>= 1) {
    if (t < st) red[t] = fmaxf(red[t], red[t + st]);
    __syncthreads();
  }
  float m = red[0];
  __syncthreads();
  float e = expf(s - m);
  red[t] = e;
  __syncthreads();
  for (int st = 128; st > 0; st >>= 1) {
    if (t < st) red[t] += red[t + st];
    __syncthreads();
  }
  float v = e * (1.f / red[0]) * ld1<F32>(amask, t);
  if (F32) ((float*)outp)[t] = v;
  else ((u16*)outp)[t] = f2bf(v);
}

extern "C" void kernel_launch(void* const* d_in, const int* in_sizes, int n_in,
                              void* d_out, int out_size, void* d_ws, size_t ws_size,
                              hipStream_t stream) {
  const void* entity = d_in[0];
  const void* rel    = d_in[1];
  const void* target = d_in[2];
  const void* amask  = d_in[3];
  const void* ew1 = d_in[4];  const void* eb1 = d_in[5];
  const void* ew2 = d_in[6];  const void* eb2 = d_in[7];
  const void* ew3 = d_in[8];  const void* eb3 = d_in[9];
  const void* rw1 = d_in[10]; const void* rb1 = d_in[11];
  const void* rw2 = d_in[12]; const void* rb2 = d_in[13];
  const void* rw3 = d_in[14]; const void* rb3 = d_in[15];
  const void* rw4 = d_in[16]; const void* rb4 = d_in[17];
  const void* rw5 = d_in[18]; const void* rb5 = d_in[19];
  const void* tw1 = d_in[20]; const void* tb1 = d_in[21];
  const void* tw2 = d_in[22]; const void* tb2 = d_in[23];
  const void* wih = d_in[24]; const void* whh = d_in[25];
  const void* bih = d_in[26]; const void* bhh = d_in[27];
  const void* hidden = d_in[28];
  const void* aw = d_in[29];  const void* ab = d_in[30];

  unsigned* ws = (unsigned*)d_ws;
  unsigned* egws = ws;                // [64]
  unsigned* rgws = ws + 64;           // [128]
  float* tpart = (float*)(ws + 192);  // [64]
  const unsigned* flag = ws + 256;    // [1]: 1 = f32 inputs

  hipLaunchKernelGGL(k_detect, dim3(1), dim3(256), 0, stream,
                     (const u16*)entity, (const u16*)rel, ws);

  hipLaunchKernelGGL((k_ent<0>), dim3(64), dim3(256), 0, stream,
                     entity, ew1, eb1, ew2, eb2, ew3, eb3, egws, flag);
  hipLaunchKernelGGL((k_ent<1>), dim3(64), dim3(256), 0, stream,
                     entity, ew1, eb1, ew2, eb2, ew3, eb3, egws, flag);

  hipLaunchKernelGGL((k_tgt<0>), dim3(256), dim3(256), 0, stream, target, tw1, tpart, flag);
  hipLaunchKernelGGL((k_tgt<1>), dim3(256), dim3(256), 0, stream, target, tw1, tpart, flag);

  hipLaunchKernelGGL((k_rel<0>), dim3(512), dim3(256), 0, stream,
                     rel, rw1, rb1, rw2, rb2, rw3, rb3, rw4, rb4, rw5, rb5, rgws, flag);
  hipLaunchKernelGGL(k_relg, dim3(512), dim3(256), 0, stream,
                     (const float*)rel, (const float*)rw1, (const float*)rb1,
                     (const float*)rw2, (const float*)rb2, (const float*)rw3,
                     (const float*)rb3, (const float*)rw4, (const float*)rb4,
                     (const float*)rw5, (const float*)rb5, rgws, flag);

  hipLaunchKernelGGL((k_fin<0>), dim3(1), dim3(256), 0, stream,
                     egws, rgws, tpart, tb1, tw2, tb2, wih, whh, bih, bhh,
                     hidden, aw, ab, amask, d_out, flag);
  hipLaunchKernelGGL((k_fin<1>), dim3(1), dim3(256), 0, stream,
                     egws, rgws, tpart, tb1, tw2, tb2, wih, whh, bih, bhh,
                     hidden, aw, ab, amask, d_out, flag);
}

// Round 4
// 1044.811 us; speedup vs baseline: 1.2315x; 1.0551x over previous
//
#include <hip/hip_runtime.h>
#include <stdint.h>

typedef unsigned short u16;
typedef short s16x8 __attribute__((ext_vector_type(8)));
typedef short s16x4 __attribute__((ext_vector_type(4)));
typedef float f32x4 __attribute__((ext_vector_type(4)));

__device__ __forceinline__ float bf2f(u16 u) {
  union { unsigned u; float f; } c; c.u = ((unsigned)u) << 16; return c.f;
}
__device__ __forceinline__ u16 f2bf(float f) {
  union { float f; unsigned u; } c; c.f = f;
  unsigned r = c.u + 0x7FFFu + ((c.u >> 16) & 1u);
  return (u16)(r >> 16);
}
__device__ __forceinline__ unsigned encf(float x) {
  union { float f; unsigned u; } c; c.f = x;
  return (c.u & 0x80000000u) ? ~c.u : (c.u | 0x80000000u);
}
__device__ __forceinline__ float decf(unsigned e) {
  union { unsigned u; float f; } c;
  c.u = (e & 0x80000000u) ? (e ^ 0x80000000u) : ~e;
  return c.f;
}
__device__ __forceinline__ f32x4 mfma16(s16x8 a, s16x8 b, f32x4 c) {
  return __builtin_amdgcn_mfma_f32_16x16x32_bf16(a, b, c, 0, 0, 0);
}
__device__ __forceinline__ float relu(float x) { return x > 0.f ? x : 0.f; }
__device__ __forceinline__ s16x4 cvt4(f32x4 a) {
  s16x4 r;
#pragma unroll
  for (int e = 0; e < 4; ++e) r[e] = (short)f2bf(a[e]);
  return r;
}

// ---- dtype-generic loaders: element index ei, F32 selects f32 vs bf16 buffers ----
template <int F32>
__device__ __forceinline__ void loadf8(const void* p, size_t ei, float* o) {
  if (F32) {
    const float* f = (const float*)p + ei;
    f32x4 a = *(const f32x4*)f;
    f32x4 b = *(const f32x4*)(f + 4);
#pragma unroll
    for (int j = 0; j < 4; ++j) { o[j] = a[j]; o[4 + j] = b[j]; }
  } else {
    s16x8 v = *(const s16x8*)((const u16*)p + ei);
#pragma unroll
    for (int j = 0; j < 8; ++j) o[j] = bf2f((u16)v[j]);
  }
}
template <int F32>
__device__ __forceinline__ s16x8 load8b(const void* p, size_t ei) {  // -> 8 bf16
  if (F32) {
    float o[8]; loadf8<1>(p, ei, o);
    s16x8 r;
#pragma unroll
    for (int j = 0; j < 8; ++j) r[j] = (short)f2bf(o[j]);
    return r;
  } else {
    return *(const s16x8*)((const u16*)p + ei);
  }
}
template <int F32>
__device__ __forceinline__ float ld1(const void* p, size_t ei) {
  return F32 ? ((const float*)p)[ei] : bf2f(((const u16*)p)[ei]);
}

// ---------------- detect dtype + init ws ----------------
// ws (u32): [0:64) egws, [64:192) rgws, [192:256) tpart, [256] flag (1 = f32)
__global__ void k_detect(const u16* __restrict__ entity, const u16* __restrict__ rel,
                         unsigned* __restrict__ ws) {
  __shared__ unsigned cnt[256];
  const int t = threadIdx.x;
  ws[t] = 0u;
  unsigned c = 0;
  for (int i = t; i < 16384; i += 256) {
    unsigned u = rel[i];
    if ((u & 0x7F80u) == 0x7F80u) ++c;  // exp all-ones: impossible in genuine bf16 data
  }
  for (int i = t; i < 8192; i += 256) {
    unsigned u = entity[i];
    if ((u & 0x7F80u) == 0x7F80u) ++c;
  }
  cnt[t] = c;
  __syncthreads();
  for (int st = 128; st > 0; st >>= 1) {
    if (t < st) cnt[t] += cnt[t + st];
    __syncthreads();
  }
  if (t == 0) ws[256] = cnt[0] ? 1u : 0u;
}

// ---------------- entity encoder: 2048 rows, 128->32->8->1, group max ----------------
template <int F32>
__global__ __launch_bounds__(256) void k_ent(
    const void* __restrict__ entity, const void* __restrict__ ew1, const void* __restrict__ eb1,
    const void* __restrict__ ew2, const void* __restrict__ eb2,
    const void* __restrict__ ew3, const void* __restrict__ eb3,
    unsigned* __restrict__ egws, const unsigned* __restrict__ flag) {
  if (*flag != (unsigned)F32) return;
  __shared__ __align__(16) u16 xl[32 * 136];
  __shared__ __align__(16) u16 w1l[32 * 136];
  __shared__ float h1l[32 * 33];
  __shared__ float h2l[32 * 9];
  const int t = threadIdx.x;
  const int row0 = blockIdx.x * 32;
#pragma unroll
  for (int p = 0; p < 2; ++p) {
    int lin = p * 256 + t, rr = lin >> 4, cc = lin & 15;
    *(s16x8*)(xl + rr * 136 + cc * 8) =
        load8b<F32>(entity, (size_t)(row0 + rr) * 128 + cc * 8);
    *(s16x8*)(w1l + rr * 136 + cc * 8) = load8b<F32>(ew1, (size_t)rr * 128 + cc * 8);
  }
  __syncthreads();
  {  // layer1
    const int r = t >> 3, g = t & 7;
    float acc[4] = {0.f, 0.f, 0.f, 0.f};
#pragma unroll 4
    for (int c = 0; c < 16; ++c) {
      s16x8 xv = *(const s16x8*)(xl + r * 136 + c * 8);
      float xf[8];
#pragma unroll
      for (int j = 0; j < 8; ++j) xf[j] = bf2f((u16)xv[j]);
#pragma unroll
      for (int s = 0; s < 4; ++s) {
        s16x8 wv = *(const s16x8*)(w1l + (g + 8 * s) * 136 + c * 8);
#pragma unroll
        for (int j = 0; j < 8; ++j) acc[s] += xf[j] * bf2f((u16)wv[j]);
      }
    }
#pragma unroll
    for (int s = 0; s < 4; ++s)
      h1l[r * 33 + g + 8 * s] = relu(acc[s] + ld1<F32>(eb1, g + 8 * s));
  }
  __syncthreads();
  {  // layer2
    const int r = t >> 3, o = t & 7;
    float a = ld1<F32>(eb2, o);
#pragma unroll 8
    for (int k = 0; k < 32; ++k) a += h1l[r * 33 + k] * ld1<F32>(ew2, o * 32 + k);
    h2l[r * 9 + o] = relu(a);
  }
  __syncthreads();
  if (t < 32) {  // layer3 + type + group max
    float s = ld1<F32>(eb3, 0);
#pragma unroll
    for (int k = 0; k < 8; ++k) s += h2l[t * 9 + k] * ld1<F32>(ew3, k);
    int ty = 0;
#pragma unroll
    for (int c = 0; c < 8; ++c) {
      s16x8 v = *(const s16x8*)(xl + t * 136 + c * 8);
#pragma unroll
      for (int j = 0; j < 8; ++j)
        if ((u16)v[j] == (u16)0x3F80) ty = c * 8 + j;
    }
    atomicMax(egws + ty, encf(s));
  }
}

// ---------------- target encoder layer1 partials ----------------
template <int F32>
__global__ __launch_bounds__(256) void k_tgt(const void* __restrict__ target,
                                             const void* __restrict__ tw1,
                                             float* __restrict__ tpart,
                                             const unsigned* __restrict__ flag) {
  if (*flag != (unsigned)F32) return;
  __shared__ float red[256];
  const int t = threadIdx.x;
  const int o = blockIdx.x >> 2, c = blockIdx.x & 3;
  float a = 0.f;
  for (int i = t; i < 2116; i += 256) {
    float xf[8], wf[8];
    loadf8<F32>(target, (size_t)c * 16928 + i * 8, xf);
    loadf8<F32>(tw1, (size_t)o * 67712 + c * 16928 + i * 8, wf);
#pragma unroll
    for (int j = 0; j < 8; ++j) a += xf[j] * wf[j];
  }
  red[t] = a;
  __syncthreads();
  for (int st = 128; st > 0; st >>= 1) {
    if (t < st) red[t] += red[t + st];
    __syncthreads();
  }
  if (t == 0) atomicAdd(tpart + o, red[0]);
}

// ---------------- relationship encoder (bf16 fallback path, original) ----------------
#define RK 2240
template <int F32>
__global__ __launch_bounds__(256) void k_rel(
    const void* __restrict__ rel, const void* __restrict__ rw1, const void* __restrict__ rb1,
    const void* __restrict__ rw2, const void* __restrict__ rb2,
    const void* __restrict__ rw3, const void* __restrict__ rb3,
    const void* __restrict__ rw4, const void* __restrict__ rb4,
    const void* __restrict__ rw5, const void* __restrict__ rb5,
    unsigned* __restrict__ rgws, const unsigned* __restrict__ flag) {
  if (*flag != (unsigned)F32) return;
  __shared__ __align__(16) unsigned char sm[53760];
  u16* smA = (u16*)sm;
  u16* smB = (u16*)(sm + 8192);
  u16* r0 = (u16*)sm;               // later h2 [128][72]
  u16* smRF = (u16*)(sm + 18432);   // rf1 [128][136]
  int* styp = (int*)(sm + 53248);

  const int t = threadIdx.x;
  const int lane = t & 63;
  const int wid = t >> 6;
  const int row0 = blockIdx.x * 128;
  const int fr = lane & 15, fq = lane >> 4;

  if (t < 128) {  // one-hot type scan, cols 0..127
    int ty = 0;
#pragma unroll 4
    for (int c = 0; c < 16; ++c) {
      s16x8 v = load8b<F32>(rel, (size_t)(row0 + t) * RK + c * 8);
#pragma unroll
      for (int j = 0; j < 8; ++j)
        if ((u16)v[j] == (u16)0x3F80) ty = c * 8 + j;
    }
    styp[t] = ty;
  }

  // ---- layer1: C[128][128] = rel_tile @ rw1^T, K=2240 ----
  const int wm = wid >> 1, wn = wid & 1;
  f32x4 acc[4][4];
#pragma unroll
  for (int i = 0; i < 4; ++i)
#pragma unroll
    for (int j = 0; j < 4; ++j) acc[i][j] = f32x4{0.f, 0.f, 0.f, 0.f};

  const size_t gA0 = (size_t)(row0 + (t >> 2)) * RK + (t & 3) * 8;
  const size_t gB0 = (size_t)(t >> 2) * RK + (t & 3) * 8;

  for (int ki = 0; ki < 70; ++ki) {
    const int k0 = ki * 32;
    s16x8 va0 = load8b<F32>(rel, gA0 + k0);
    s16x8 va1 = load8b<F32>(rel, gA0 + (size_t)64 * RK + k0);
    s16x8 vb0 = load8b<F32>(rw1, gB0 + k0);
    s16x8 vb1 = load8b<F32>(rw1, gB0 + (size_t)64 * RK + k0);
    __syncthreads();
    *(s16x8*)(smA + t * 8) = va0;
    *(s16x8*)(smA + 2048 + t * 8) = va1;
    *(s16x8*)(smB + t * 8) = vb0;
    *(s16x8*)(smB + 2048 + t * 8) = vb1;
    __syncthreads();
    s16x8 a[4], b[4];
#pragma unroll
    for (int i = 0; i < 4; ++i)
      a[i] = *(const s16x8*)(smA + (wm * 64 + i * 16 + fr) * 32 + fq * 8);
#pragma unroll
    for (int j = 0; j < 4; ++j)
      b[j] = *(const s16x8*)(smB + (wn * 64 + j * 16 + fr) * 32 + fq * 8);
#pragma unroll
    for (int i = 0; i < 4; ++i)
#pragma unroll
      for (int j = 0; j < 4; ++j) acc[i][j] = mfma16(a[i], b[j], acc[i][j]);
  }
  __syncthreads();

  // epilogue L1 -> smRF[128][136] bf16
#pragma unroll
  for (int j = 0; j < 4; ++j) {
    const int col = wn * 64 + j * 16 + fr;
    const float bias = ld1<F32>(rb1, col);
#pragma unroll
    for (int i = 0; i < 4; ++i) {
      const int rbase = wm * 64 + i * 16 + fq * 4;
#pragma unroll
      for (int r = 0; r < 4; ++r)
        smRF[(rbase + r) * 136 + col] = f2bf(relu(acc[i][j][r] + bias));
    }
  }
  __syncthreads();

  // ---- layers 2-5: VALU, thread t owns row t ----
  if (t < 128) {
    const u16* rfrow = smRF + t * 136;
    for (int o = 0; o < 64; ++o) {
      float a = ld1<F32>(rb2, o);
      for (int k = 0; k < 128; k += 8) {
        float wf[8];
        loadf8<F32>(rw2, o * 128 + k, wf);
#pragma unroll
        for (int j = 0; j < 8; ++j) a += bf2f(rfrow[k + j]) * wf[j];
      }
      r0[t * 72 + o] = f2bf(relu(a));
    }
    const u16* h2row = r0 + t * 72;
    float h3[32];
#pragma unroll
    for (int o = 0; o < 32; ++o) {
      float a = ld1<F32>(rb3, o);
      for (int k = 0; k < 64; k += 8) {
        float wf[8];
        loadf8<F32>(rw3, o * 64 + k, wf);
#pragma unroll
        for (int j = 0; j < 8; ++j) a += bf2f(h2row[k + j]) * wf[j];
      }
      h3[o] = relu(a);
    }
    float h4[8];
#pragma unroll
    for (int o = 0; o < 8; ++o) {
      float a = ld1<F32>(rb4, o);
#pragma unroll
      for (int k = 0; k < 32; ++k) a += h3[k] * ld1<F32>(rw4, o * 32 + k);
      h4[o] = relu(a);
    }
    float s = ld1<F32>(rb5, 0);
#pragma unroll
    for (int k = 0; k < 8; ++k) s += h4[k] * ld1<F32>(rw5, k);
    atomicMax(rgws + styp[t], encf(s));
  }
}

// ---------------- relationship encoder, f32 fast path ----------------
// 512 threads (8 waves, wave-tile 32x64). BK=64, double-buffered LDS with
// depth-1 register prefetch, ONE barrier per K-step. Staging is
// row-contiguous per instruction: 16 lanes x f32x4 = 256 B of one row
// (4 rows / 16 seq cache lines per instr, each line touched once) — fixes
// the VMEM request-throughput bottleneck (5 B/cyc/CU in r3). LDS is
// [128][64]bf16 with byte ^= (row&7)<<4 XOR swizzle (frag reads would be
// 16-way conflicted at 128 B row stride otherwise). Numerics bit-identical
// to validated k_rel<1>: f2bf at staging, same 32-wide K-slice MFMA order.
__global__ __launch_bounds__(512, 2) void k_relg(
    const float* __restrict__ rel, const float* __restrict__ rw1, const float* __restrict__ rb1,
    const float* __restrict__ rw2, const float* __restrict__ rb2,
    const float* __restrict__ rw3, const float* __restrict__ rb3,
    const float* __restrict__ rw4, const float* __restrict__ rb4,
    const float* __restrict__ rw5, const float* __restrict__ rb5,
    unsigned* __restrict__ rgws, const unsigned* __restrict__ flag) {
  if (*flag != 1u) return;
  // LDS: buf0 A@0 B@16384, buf1 A@32768 B@49152 (each [128][64]bf16 = 16 KB).
  // After K-loop: smRF[128][136]u16 @0 (34816), h2[128][72]u16 @36864 (18432).
  __shared__ __align__(16) unsigned char sm[65536];
  const int t = threadIdx.x;
  const int lane = t & 63;
  const int wid = t >> 6;                 // 0..7
  const int row0 = blockIdx.x * 128;
  const int fr = lane & 15, fq = lane >> 4;
  const int wm = wid >> 1, wn = wid & 1;  // wave tile: rows wm*32.., cols wn*64..

  // staging: wave wid owns rows wid*16..+16; instr j: lane -> row wid*16+j*4+(lane>>4),
  // f32 col (lane&15)*4  => 16 lanes = 256 B contiguous of one row.
  const int srow = wid * 16 + (lane >> 4);
  const int scol = (lane & 15) * 4;
  const float* pA = rel + (size_t)(row0 + srow) * RK + scol;
  const float* pB = rw1 + (size_t)srow * RK + scol;

  f32x4 acc[2][4];
#pragma unroll
  for (int i = 0; i < 2; ++i)
#pragma unroll
    for (int j = 0; j < 4; ++j) acc[i][j] = f32x4{0.f, 0.f, 0.f, 0.f};

  f32x4 preA[4], preB[4];
  auto lstep = [&](int k0) {
#pragma unroll
    for (int j = 0; j < 4; ++j) {
      preA[j] = *(const f32x4*)(pA + (size_t)(j * 4) * RK + k0);
      preB[j] = *(const f32x4*)(pB + (size_t)(j * 4) * RK + k0);
    }
  };
  auto wstep = [&](unsigned char* base) {
    unsigned char* dA = base;
    unsigned char* dB = base + 16384;
#pragma unroll
    for (int j = 0; j < 4; ++j) {
      const int rowL = wid * 16 + j * 4 + (lane >> 4);
      const int boff = rowL * 128 + (((lane & 15) * 8) ^ ((rowL & 7) << 4));
      *(s16x4*)(dA + boff) = cvt4(preA[j]);
      *(s16x4*)(dB + boff) = cvt4(preB[j]);
    }
  };

  // prologue: stage K-step 0 into buffer 0
  lstep(0);
  wstep(sm);
  __syncthreads();

  int ty = 0;
#pragma unroll 1
  for (int ks = 0; ks < 35; ++ks) {
    if (ks < 34) lstep((ks + 1) * 64);  // next-step loads in flight across MFMA phase
    const unsigned char* bA = sm + (ks & 1) * 32768;
    const unsigned char* bB = bA + 16384;
#pragma unroll
    for (int k2 = 0; k2 < 2; ++k2) {  // two 32-wide K-slices, original order
      s16x8 a[2], b[4];
#pragma unroll
      for (int i = 0; i < 2; ++i) {
        const int ar = wm * 32 + i * 16 + fr;
        a[i] = *(const s16x8*)(bA + ar * 128 + ((k2 * 64 + fq * 16) ^ ((ar & 7) << 4)));
      }
#pragma unroll
      for (int j = 0; j < 4; ++j) {
        const int br = wn * 64 + j * 16 + fr;
        b[j] = *(const s16x8*)(bB + br * 128 + ((k2 * 64 + fq * 16) ^ ((br & 7) << 4)));
      }
#pragma unroll
      for (int i = 0; i < 2; ++i)
#pragma unroll
        for (int j = 0; j < 4; ++j) acc[i][j] = mfma16(a[i], b[j], acc[i][j]);
    }
    if (ks < 2 && t < 128) {  // one-hot type scan from staged tile (cols ks*64..+64)
#pragma unroll
      for (int c = 0; c < 8; ++c) {
        s16x8 v = *(const s16x8*)(bA + t * 128 + ((c * 16) ^ ((t & 7) << 4)));
#pragma unroll
        for (int jj = 0; jj < 8; ++jj)
          if ((u16)v[jj] == (u16)0x3F80) ty = ks * 64 + c * 8 + jj;
      }
    }
    if (ks < 34) wstep(sm + ((ks + 1) & 1) * 32768);
    __syncthreads();  // next buffer visible; current buffer free
  }

  // ---- epilogue L1 -> smRF[128][136] bf16 (aliases staging buffers) ----
  u16* smRF = (u16*)sm;
  u16* h2 = (u16*)(sm + 36864);
#pragma unroll
  for (int j = 0; j < 4; ++j) {
    const int col = wn * 64 + j * 16 + fr;
    const float bias = rb1[col];
#pragma unroll
    for (int i = 0; i < 2; ++i) {
      const int rbase = wm * 32 + i * 16 + fq * 4;
#pragma unroll
      for (int r = 0; r < 4; ++r)
        smRF[(rbase + r) * 136 + col] = f2bf(relu(acc[i][j][r] + bias));
    }
  }
  __syncthreads();

  // ---- layers 2-5: VALU, thread t owns row t (original arithmetic order) ----
  if (t < 128) {
    const u16* rfrow = smRF + t * 136;
    for (int o = 0; o < 64; ++o) {
      float a = rb2[o];
      for (int k = 0; k < 128; k += 8) {
        float wf[8];
        loadf8<1>(rw2, (size_t)o * 128 + k, wf);
#pragma unroll
        for (int j = 0; j < 8; ++j) a += bf2f(rfrow[k + j]) * wf[j];
      }
      h2[t * 72 + o] = f2bf(relu(a));
    }
    const u16* h2row = h2 + t * 72;
    float h3[32];
#pragma unroll
    for (int o = 0; o < 32; ++o) {
      float a = rb3[o];
      for (int k = 0; k < 64; k += 8) {
        float wf[8];
        loadf8<1>(rw3, (size_t)o * 64 + k, wf);
#pragma unroll
        for (int j = 0; j < 8; ++j) a += bf2f(h2row[k + j]) * wf[j];
      }
      h3[o] = relu(a);
    }
    float h4[8];
#pragma unroll
    for (int o = 0; o < 8; ++o) {
      float a = rb4[o];
#pragma unroll
      for (int k = 0; k < 32; ++k) a += h3[k] * rw4[o * 32 + k];
      h4[o] = relu(a);
    }
    float s = rb5[0];
#pragma unroll
    for (int k = 0; k < 8; ++k) s += h4[k] * rw5[k];
    atomicMax(rgws + ty, encf(s));
  }
}

// ---------------- finale ----------------
template <int F32>
__global__ __launch_bounds__(256) void k_fin(
    const unsigned* __restrict__ egws, const unsigned* __restrict__ rgws,
    const float* __restrict__ tpart, const void* __restrict__ tb1,
    const void* __restrict__ tw2, const void* __restrict__ tb2,
    const void* __restrict__ wih, const void* __restrict__ whh,
    const void* __restrict__ bih, const void* __restrict__ bhh,
    const void* __restrict__ hidden, const void* __restrict__ aw,
    const void* __restrict__ ab, const void* __restrict__ amask,
    void* __restrict__ outp, const unsigned* __restrict__ flag) {
  if (*flag != (unsigned)F32) return;
  __shared__ float env[208];
  __shared__ float th1[64];
  __shared__ float gx[384], gh[384];
  __shared__ float hv[128], hid[128];
  __shared__ float red[256];
  const int t = threadIdx.x;
  if (t < 64) {
    unsigned e = egws[t];
    env[t] = e ? decf(e) : 0.f;
    th1[t] = relu(tpart[t] + ld1<F32>(tb1, t));
  }
  if (t >= 64 && t < 192) {
    unsigned e = rgws[t - 64];
    env[t] = e ? decf(e) : 0.f;
  }
  if (t < 128) hid[t] = ld1<F32>(hidden, t);
  __syncthreads();
  if (t < 16) {
    float a = ld1<F32>(tb2, t);
    for (int k = 0; k < 64; k += 8) {
      float wf[8];
      loadf8<F32>(tw2, t * 64 + k, wf);
#pragma unroll
      for (int j = 0; j < 8; ++j) a += th1[k + j] * wf[j];
    }
    env[192 + t] = a;
  }
  __syncthreads();
  for (int o = t; o < 384; o += 256) {
    float ax = ld1<F32>(bih, o);
#pragma unroll 2
    for (int c = 0; c < 26; ++c) {
      float wf[8];
      loadf8<F32>(wih, (size_t)o * 208 + c * 8, wf);
#pragma unroll
      for (int j = 0; j < 8; ++j) ax += env[c * 8 + j] * wf[j];
    }
    gx[o] = ax;
    float ah = ld1<F32>(bhh, o);
#pragma unroll 2
    for (int c = 0; c < 16; ++c) {
      float wf[8];
      loadf8<F32>(whh, (size_t)o * 128 + c * 8, wf);
#pragma unroll
      for (int j = 0; j < 8; ++j) ah += hid[c * 8 + j] * wf[j];
    }
    gh[o] = ah;
  }
  __syncthreads();
  if (t < 128) {
    float r = 1.f / (1.f + expf(-(gx[t] + gh[t])));
    float z = 1.f / (1.f + expf(-(gx[128 + t] + gh[128 + t])));
    float n = tanhf(gx[256 + t] + r * gh[256 + t]);
    hv[t] = (1.f - z) * n + z * hid[t];
  }
  __syncthreads();
  float s = ld1<F32>(ab, t);
#pragma unroll 4
  for (int c = 0; c < 16; ++c) {
    float wf[8];
    loadf8<F32>(aw, (size_t)t * 128 + c * 8, wf);
#pragma unroll
    for (int j = 0; j < 8; ++j) s += hv[c * 8 + j] * wf[j];
  }
  red[t] = s;
  __syncthreads();
  for (int st = 128; st > 0; st >>= 1) {
    if (t < st) red[t] = fmaxf(red[t], red[t + st]);
    __syncthreads();
  }
  float m = red[0];
  __syncthreads();
  float e = expf(s - m);
  red[t] = e;
  __syncthreads();
  for (int st = 128; st > 0; st >>= 1) {
    if (t < st) red[t] += red[t + st];
    __syncthreads();
  }
  float v = e * (1.f / red[0]) * ld1<F32>(amask, t);
  if (F32) ((float*)outp)[t] = v;
  else ((u16*)outp)[t] = f2bf(v);
}

extern "C" void kernel_launch(void* const* d_in, const int* in_sizes, int n_in,
                              void* d_out, int out_size, void* d_ws, size_t ws_size,
                              hipStream_t stream) {
  const void* entity = d_in[0];
  const void* rel    = d_in[1];
  const void* target = d_in[2];
  const void* amask  = d_in[3];
  const void* ew1 = d_in[4];  const void* eb1 = d_in[5];
  const void* ew2 = d_in[6];  const void* eb2 = d_in[7];
  const void* ew3 = d_in[8];  const void* eb3 = d_in[9];
  const void* rw1 = d_in[10]; const void* rb1 = d_in[11];
  const void* rw2 = d_in[12]; const void* rb2 = d_in[13];
  const void* rw3 = d_in[14]; const void* rb3 = d_in[15];
  const void* rw4 = d_in[16]; const void* rb4 = d_in[17];
  const void* rw5 = d_in[18]; const void* rb5 = d_in[19];
  const void* tw1 = d_in[20]; const void* tb1 = d_in[21];
  const void* tw2 = d_in[22]; const void* tb2 = d_in[23];
  const void* wih = d_in[24]; const void* whh = d_in[25];
  const void* bih = d_in[26]; const void* bhh = d_in[27];
  const void* hidden = d_in[28];
  const void* aw = d_in[29];  const void* ab = d_in[30];

  unsigned* ws = (unsigned*)d_ws;
  unsigned* egws = ws;                // [64]
  unsigned* rgws = ws + 64;           // [128]
  float* tpart = (float*)(ws + 192);  // [64]
  const unsigned* flag = ws + 256;    // [1]: 1 = f32 inputs

  hipLaunchKernelGGL(k_detect, dim3(1), dim3(256), 0, stream,
                     (const u16*)entity, (const u16*)rel, ws);

  hipLaunchKernelGGL((k_ent<0>), dim3(64), dim3(256), 0, stream,
                     entity, ew1, eb1, ew2, eb2, ew3, eb3, egws, flag);
  hipLaunchKernelGGL((k_ent<1>), dim3(64), dim3(256), 0, stream,
                     entity, ew1, eb1, ew2, eb2, ew3, eb3, egws, flag);

  hipLaunchKernelGGL((k_tgt<0>), dim3(256), dim3(256), 0, stream, target, tw1, tpart, flag);
  hipLaunchKernelGGL((k_tgt<1>), dim3(256), dim3(256), 0, stream, target, tw1, tpart, flag);

  hipLaunchKernelGGL((k_rel<0>), dim3(512), dim3(256), 0, stream,
                     rel, rw1, rb1, rw2, rb2, rw3, rb3, rw4, rb4, rw5, rb5, rgws, flag);
  hipLaunchKernelGGL(k_relg, dim3(512), dim3(512), 0, stream,
                     (const float*)rel, (const float*)rw1, (const float*)rb1,
                     (const float*)rw2, (const float*)rb2, (const float*)rw3,
                     (const float*)rb3, (const float*)rw4, (const float*)rb4,
                     (const float*)rw5, (const float*)rb5, rgws, flag);

  hipLaunchKernelGGL((k_fin<0>), dim3(1), dim3(256), 0, stream,
                     egws, rgws, tpart, tb1, tw2, tb2, wih, whh, bih, bhh,
                     hidden, aw, ab, amask, d_out, flag);
  hipLaunchKernelGGL((k_fin<1>), dim3(1), dim3(256), 0, stream,
                     egws, rgws, tpart, tb1, tw2, tb2, wih, whh, bih, bhh,
                     hidden, aw, ab, amask, d_out, flag);
}